// Round 8
// baseline (124.098 us; speedup 1.0000x reference)
//
#include <hip/hip_runtime.h>
#include <hip/hip_bf16.h>
#include <math.h>

#define N 2048
#define NC 8

// ws layout:
//   [0, 64)             : double acc[8]        (zeroed by k_prep block 0)
//   [64, 64+64K)        : float  A[8][2048]
//   [64+64K, 64+128K)   : int    lohi[8][2048] (lo | hi<<16, per ORIGINAL row)
//   [64+128K, +4)       : unsigned counter     (ticket for fused finalize)

#if __has_builtin(__builtin_amdgcn_exp2f)
__device__ __forceinline__ float fexp2(float x) { return __builtin_amdgcn_exp2f(x); }
#else
__device__ __forceinline__ float fexp2(float x) { return exp2f(x); }
#endif
#if __has_builtin(__builtin_amdgcn_logf)
__device__ __forceinline__ float flog2(float x) { return __builtin_amdgcn_logf(x); }
#else
__device__ __forceinline__ float flog2(float x) { return log2f(x); }
#endif

#define INV_LN2 1.4426950408889634f
#define LN2_D   0.6931471805599453
#define CLAMP2  (-144.26950408889634f)   /* -100/ln2 : clamp in log2 domain */

// ---------------- Kernel 1: fused A-sum + counting-rank GT + acc zeroing ------
// 256 blocks total (dispatch-rate ceiling ~40 blocks/us fits r2/r5/r7 k_bce).
// blocks [0,128):   A[j] = sum_i |s_j - s_i|  (col = b>>4, 16 chunks of 128 j)
// blocks [128,256): counting-rank windows     (col = b2>>4, 16 chunks of 128 j)
__global__ __launch_bounds__(256) void k_prep(const float* __restrict__ logits,
                                              const float* __restrict__ dur,
                                              const int* __restrict__ ev,
                                              float* __restrict__ A,
                                              int* __restrict__ lohi,
                                              double* __restrict__ acc,
                                              unsigned* __restrict__ counter) {
    __shared__ float s[N];                   // 8 KB   (asum)
    __shared__ double part[256];             // 2 KB   (asum)
    __shared__ unsigned long long keys[N];   // 16 KB  (sortgt)
    __shared__ int pr[256], pv[256];         // 2 KB   (sortgt)

    int b = blockIdx.x;
    int tid = threadIdx.x;

    if (b == 0) {  // zero accumulators + ticket for k_bce (stream-ordered)
        if (tid < 8) acc[tid] = 0.0;
        else if (tid == 8) counter[0] = 0u;
    }

    if (b < 128) {
        // ---- A-sum: 128 j's per block, 2 i-slices of 1024 ----
        int col = b >> 4, chunk = b & 15;
        for (int k = 0; k < N / 256; ++k) {
            int i = tid + k * 256;
            s[i] = logits[i * NC + col];
        }
        __syncthreads();
        int jl = tid & 127, slice = tid >> 7;
        int j = chunk * 128 + jl;
        float sj = s[j];
        int base = slice * 1024;
        double a0 = 0.0, a1 = 0.0, a2 = 0.0, a3 = 0.0;
        #pragma unroll 2
        for (int i = 0; i < 1024; i += 4) {
            a0 += (double)fabsf(sj - s[base + i]);
            a1 += (double)fabsf(sj - s[base + i + 1]);
            a2 += (double)fabsf(sj - s[base + i + 2]);
            a3 += (double)fabsf(sj - s[base + i + 3]);
        }
        part[tid] = (a0 + a1) + (a2 + a3);
        __syncthreads();
        if (tid < 128) {
            A[col * N + j] = (float)(part[tid] + part[tid + 128]);
        }
    } else {
        // ---- counting-rank GT windows ----
        // key = (dur_bits<<32)|(i<<1)|e : ascending u64 == stable ascending by d
        int b2 = b - 128;
        int col = b2 >> 4, chunk = b2 & 15;
        for (int k = 0; k < N / 256; ++k) {
            int i = tid + k * 256;
            unsigned int db = __float_as_uint(dur[i * NC + col]);  // dur in [0,1)
            int e = ev[i * NC + col];
            keys[i] = ((unsigned long long)db << 32) | (unsigned int)((i << 1) | e);
        }
        __syncthreads();
        int jl = tid & 127, slice = tid >> 7;
        int j = chunk * 128 + jl;
        unsigned long long kj = keys[j];
        int base = slice * 1024;
        int rank = 0, evlt = 0;
        #pragma unroll 4
        for (int i = 0; i < 1024; ++i) {
            unsigned long long ki = keys[base + i];
            int lt = (ki < kj) ? 1 : 0;
            rank += lt;
            evlt += lt & (int)(ki & 1ull);
        }
        pr[tid] = rank;
        pv[tid] = evlt;
        __syncthreads();
        if (tid < 128) {
            int r = pr[tid] + pr[tid + 128];
            int v = pv[tid] + pv[tid + 128];
            int e = (int)(kj & 1ull);
            int hi = e ? (r + 1) : N;
            lohi[col * N + j] = v | (hi << 16);
        }
    }
}

// ---------------- Kernel 2: softmax+BCE, ILP-4, 8 rows/wave, 512 blocks -------
// Dispatch-model test: 512 blocks (vs r7's 2048) with 4x work per block.
// Each wave: 2 reps x 4 interleaved row-chains (ILP-4 on fma/exp/log chains and
// on every shuffle-reduce round). Register cache sv/av (64 VGPR) + 4x7 row
// state ~= 110 VGPR — plain __launch_bounds__(256) ONLY (min-waves clamps and
// 1024-thread blocks collapse the budget and spill: r3/r4/r6).
// All accumulation in log2 units; multiply by ln2 once at the atomic.
__global__ __launch_bounds__(256) void k_bce(const float* __restrict__ logits,
                                             const float* __restrict__ A,
                                             const int* __restrict__ lohi,
                                             double* __restrict__ acc,
                                             unsigned* __restrict__ counter,
                                             float* __restrict__ out) {
    int col = blockIdx.x >> 6;   // 0..7
    int rg  = blockIdx.x & 63;   // 0..63 (32 rows each)
    __shared__ union SU {
        float2 sa[N];            // {s/ln2, A/ln2} — dead after reg-cache load
        double bsum[4];          // block reduction buffer (aliases sa[0..3])
    } u;                         // exactly 16384 B
    int tid = threadIdx.x;
    int wave = tid >> 6, lane = tid & 63;

    #pragma unroll
    for (int k = 0; k < 8; ++k) {
        int i = tid + (k << 8);
        u.sa[i] = make_float2(logits[i * NC + col] * INV_LN2,
                              A[col * N + i] * INV_LN2);
    }
    __syncthreads();

    // one-time LDS -> register cache
    float sv[32], av[32];
    #pragma unroll
    for (int k = 0; k < 32; ++k) {
        float2 v = u.sa[lane + (k << 6)];
        sv[k] = v.x;
        av[k] = v.y;
    }
    __syncthreads();   // sa dead from here; u.bsum written below

    double rsum = 0.0;   // in log2 units

    #pragma unroll
    for (int rep = 0; rep < 2; ++rep) {
        int row0 = (rg << 5) + (wave << 3) + (rep << 2);

        float sc[4];
        int lh[4];
        #pragma unroll
        for (int c = 0; c < 4; ++c) {
            sc[c] = (float)(N - 1 - 2 * (row0 + c));
            lh[c] = lohi[col * N + row0 + c];     // prefetch: latency overlaps pass 1
        }

        // pass 1: 4 interleaved row-max chains
        float mm[4] = {-INFINITY, -INFINITY, -INFINITY, -INFINITY};
        #pragma unroll
        for (int k = 0; k < 32; ++k) {
            #pragma unroll
            for (int c = 0; c < 4; ++c)
                mm[c] = fmaxf(mm[c], fmaf(sc[c], sv[k], -av[k]));
        }
        #pragma unroll
        for (int off = 32; off > 0; off >>= 1) {
            #pragma unroll
            for (int c = 0; c < 4; ++c)
                mm[c] = fmaxf(mm[c], __shfl_xor(mm[c], off, 64));
        }

        // pass 2: 4 interleaved sum-exp chains
        float se[4] = {0.0f, 0.0f, 0.0f, 0.0f};
        #pragma unroll
        for (int k = 0; k < 32; ++k) {
            #pragma unroll
            for (int c = 0; c < 4; ++c)
                se[c] += fexp2(fmaf(sc[c], sv[k], -(av[k] + mm[c])));
        }
        #pragma unroll
        for (int off = 32; off > 0; off >>= 1) {
            #pragma unroll
            for (int c = 0; c < 4; ++c)
                se[c] += __shfl_xor(se[c], off, 64);
        }

        float C2[4];
        unsigned lo[4], wl[4];
        #pragma unroll
        for (int c = 0; c < 4; ++c) {
            float L2 = flog2(se[c]);
            rsum -= 2048.0 * (double)L2;          // the -n*L2 term of sum l1
            C2[c] = CLAMP2 + L2;                  // clamp threshold in (t-m) units
            lo[c] = (unsigned)(lh[c] & 0xffff);
            wl[c] = (unsigned)((lh[c] >> 16) & 0xffff) - lo[c];
        }

        // pass 3: a1 = sum max(log2(S-e),C2) ; a2 = sum_window (max(tm,C2)-mx2)
        float a1[4] = {0.0f, 0.0f, 0.0f, 0.0f};
        float a2[4] = {0.0f, 0.0f, 0.0f, 0.0f};
        #pragma unroll
        for (int k = 0; k < 32; ++k) {
            int j = lane + (k << 6);
            #pragma unroll
            for (int c = 0; c < 4; ++c) {
                float tm  = fmaf(sc[c], sv[k], -(av[k] + mm[c]));
                float e   = fexp2(tm);
                float mx2 = fmaxf(flog2(se[c] - e), C2[c]);  // S >= e
                a1[c] += mx2;
                float w = ((unsigned)(j - lo[c]) < wl[c])
                            ? (fmaxf(tm, C2[c]) - mx2) : 0.0f;
                a2[c] += w;
            }
        }
        #pragma unroll
        for (int off = 32; off > 0; off >>= 1) {
            #pragma unroll
            for (int c = 0; c < 4; ++c) {
                a1[c] += __shfl_xor(a1[c], off, 64);
                a2[c] += __shfl_xor(a2[c], off, 64);
            }
        }
        #pragma unroll
        for (int c = 0; c < 4; ++c) {
            float y = 1.0f / (float)wl[c];
            rsum += (double)a1[c] + (double)y * (double)a2[c];
        }
    }

    // block combine -> 1 atomic/block -> ticket finalize in last block
    if (lane == 0) u.bsum[wave] = rsum;
    __syncthreads();
    if (tid == 0) {
        double tot = (u.bsum[0] + u.bsum[1]) + (u.bsum[2] + u.bsum[3]);
        atomicAdd(&acc[col], LN2_D * tot);
        __threadfence();
        unsigned old = atomicAdd(counter, 1u);
        if (old == (unsigned)(NC * 64 - 1)) {  // last of 512 blocks: masked mean
            __threadfence();
            float ssum = 0.0f;
            int cnt = 0;
            for (int c = 0; c < NC; ++c) {
                double av2 = atomicAdd(&acc[c], 0.0);  // device-scope coherent read
                float lc = (float)(-av2 / ((double)N * (double)N));
                if (lc > 0.0f) { ssum += lc; cnt++; }
            }
            out[0] = ssum / (float)(cnt > 0 ? cnt : 1);
        }
    }
}

extern "C" void kernel_launch(void* const* d_in, const int* in_sizes, int n_in,
                              void* d_out, int out_size, void* d_ws, size_t ws_size,
                              hipStream_t stream) {
    const float* logits    = (const float*)d_in[0];
    const int*   events    = (const int*)d_in[1];
    const float* durations = (const float*)d_in[2];
    float* out = (float*)d_out;

    char* ws = (char*)d_ws;
    double*   acc     = (double*)ws;
    float*    A       = (float*)(ws + 64);
    int*      lohi    = (int*)(ws + 64 + (size_t)NC * N * sizeof(float));
    unsigned* counter = (unsigned*)(ws + 64 + 2 * (size_t)NC * N * sizeof(float));

    k_prep<<<dim3(256), 256, 0, stream>>>(logits, durations, events, A, lohi, acc, counter);
    k_bce<<<dim3(NC * 64), 256, 0, stream>>>(logits, A, lohi, acc, counter, out);
}

// Round 9
// 102.561 us; speedup vs baseline: 1.2100x; 1.2100x over previous
//
#include <hip/hip_runtime.h>
#include <hip/hip_bf16.h>
#include <math.h>

#define N 2048
#define NC 8

// ws layout:
//   [0, 64)              : double acc[8]          (zeroed by k_prep block 0)
//   [64, 64+128K)        : float2 pack[8][2048]   {s/ln2, A/ln2} packed by k_prep
//   [64+128K, 64+192K)   : int    lohi[8][2048]   (lo | hi<<16, per ORIGINAL row)
//   [64+192K, +4)        : unsigned counter       (ticket for fused finalize)

#if __has_builtin(__builtin_amdgcn_exp2f)
__device__ __forceinline__ float fexp2(float x) { return __builtin_amdgcn_exp2f(x); }
#else
__device__ __forceinline__ float fexp2(float x) { return exp2f(x); }
#endif
#if __has_builtin(__builtin_amdgcn_logf)
__device__ __forceinline__ float flog2(float x) { return __builtin_amdgcn_logf(x); }
#else
__device__ __forceinline__ float flog2(float x) { return log2f(x); }
#endif

#define INV_LN2 1.4426950408889634f
#define LN2_D   0.6931471805599453
#define CLAMP2  (-144.26950408889634f)   /* -100/ln2 : clamp in log2 domain */

// ---------------- Kernel 1: fused A-sum + counting-rank GT + packing ----------
// blocks [0,256):   A[j] = sum_i |s_j - s_i| ; write pack[col][j] = {s,A}/ln2
// blocks [256,512): counting-rank windows -> lohi
__global__ __launch_bounds__(256) void k_prep(const float* __restrict__ logits,
                                              const float* __restrict__ dur,
                                              const int* __restrict__ ev,
                                              float2* __restrict__ pack,
                                              int* __restrict__ lohi,
                                              double* __restrict__ acc,
                                              unsigned* __restrict__ counter) {
    __shared__ float s[N];                   // 8 KB   (asum)
    __shared__ double part[256];             // 2 KB   (asum)
    __shared__ unsigned long long keys[N];   // 16 KB  (sortgt)
    __shared__ int pr[256], pv[256];         // 2 KB   (sortgt)

    int b = blockIdx.x;
    int tid = threadIdx.x;

    if (b == 0) {  // zero accumulators + ticket for k_bce (stream-ordered)
        if (tid < 8) acc[tid] = 0.0;
        else if (tid == 8) counter[0] = 0u;
    }

    if (b < 256) {
        // ---- A-sum, 64 j's per block, 4 i-slices of 512 (f64: exactness) ----
        int col = b >> 5, chunk = b & 31;
        for (int k = 0; k < N / 256; ++k) {
            int i = tid + k * 256;
            s[i] = logits[i * NC + col];
        }
        __syncthreads();
        int jl = tid & 63, slice = tid >> 6;
        int j = chunk * 64 + jl;
        float sj = s[j];
        int base = slice * 512;
        double a0 = 0.0, a1 = 0.0, a2 = 0.0, a3 = 0.0;
        #pragma unroll 2
        for (int i = 0; i < 512; i += 4) {
            a0 += (double)fabsf(sj - s[base + i]);
            a1 += (double)fabsf(sj - s[base + i + 1]);
            a2 += (double)fabsf(sj - s[base + i + 2]);
            a3 += (double)fabsf(sj - s[base + i + 3]);
        }
        part[tid] = (a0 + a1) + (a2 + a3);
        __syncthreads();
        if (tid < 64) {
            double v = ((part[tid] + part[tid + 64]) + part[tid + 128]) + part[tid + 192];
            pack[col * N + j] = make_float2(sj * INV_LN2, (float)v * INV_LN2);
        }
    } else {
        // ---- counting-rank GT windows ----
        // key = (dur_bits<<32)|(i<<1)|e : ascending u64 == stable ascending by d
        int b2 = b - 256;
        int col = b2 >> 5, chunk = b2 & 31;
        for (int k = 0; k < N / 256; ++k) {
            int i = tid + k * 256;
            unsigned int db = __float_as_uint(dur[i * NC + col]);  // dur in [0,1)
            int e = ev[i * NC + col];
            keys[i] = ((unsigned long long)db << 32) | (unsigned int)((i << 1) | e);
        }
        __syncthreads();
        int jl = tid & 63, slice = tid >> 6;
        int j = chunk * 64 + jl;
        unsigned long long kj = keys[j];
        int base = slice * 512;
        int rank = 0, evlt = 0;
        #pragma unroll 4
        for (int i = 0; i < 512; ++i) {
            unsigned long long ki = keys[base + i];
            int lt = (ki < kj) ? 1 : 0;
            rank += lt;
            evlt += lt & (int)(ki & 1ull);
        }
        pr[tid] = rank;
        pv[tid] = evlt;
        __syncthreads();
        if (tid < 64) {
            int r = ((pr[tid] + pr[tid + 64]) + pr[tid + 128]) + pr[tid + 192];
            int v = ((pv[tid] + pv[tid + 64]) + pv[tid + 128]) + pv[tid + 192];
            int e = (int)(kj & 1ull);
            int hi = e ? (r + 1) : N;
            lohi[col * N + j] = v | (hi << 16);
        }
    }
}

// ---------------- Kernel 2: softmax+BCE, m0-frame incremental exp -------------
// Wave handles 4 consecutive rows (c=0..3). t_c[j] = tb[j] - 2c*s_j, so in the
// row-0 max frame: E_c = E_{c-1} * g_j, g_j = 2^(-2 s_j). Rows 1..3 need NO max
// pass and NO exp — one v_mul each. Range-safe: |2c*s| <= ~27 -> se <= 2^38;
// se >= E by RN monotonicity of non-negative sums (log2(se-E) well-defined).
//   log2 p_c[j] = x_c - L2_c,  log2(1-p) = log2(se_c - E_c) - L2_c
// Reg cache sv[32]+tb[32] only (64 VGPR; g recomputed inline) -> target <=128
// VGPR for 4 waves/SIMD cap. Plain __launch_bounds__(256) ONLY (clamps spill:
// r3/r4/r6). Grid 1024 blocks x 16 rows: 1/4 the per-wave lifetime of r8.
__global__ __launch_bounds__(256) void k_bce(const float2* __restrict__ pack,
                                             const int* __restrict__ lohi,
                                             double* __restrict__ acc,
                                             unsigned* __restrict__ counter,
                                             float* __restrict__ out) {
    int col = blockIdx.x >> 7;   // 0..7
    int rg  = blockIdx.x & 127;  // 0..127 (16 rows each)
    __shared__ union SU {
        float2 sa[N];            // staged {s/ln2, A/ln2} — dead after reg cache
        float4 sa4[N / 2];
        double bsum[4];          // block reduction buffer (aliases sa[0..3])
    } u;                         // exactly 16384 B
    int tid = threadIdx.x;
    int wave = tid >> 6, lane = tid & 63;

    // fully-coalesced staging: 16 KB contiguous, float4
    const float4* p4 = (const float4*)(pack + (size_t)col * N);
    #pragma unroll
    for (int k = 0; k < 4; ++k) {
        int i = tid + (k << 8);
        u.sa4[i] = p4[i];
    }
    __syncthreads();

    int row0 = (rg << 4) + (wave << 2);
    float sc0 = (float)(N - 1 - 2 * row0);

    // one-time LDS -> register cache: sv = s/ln2, tb = row-0 scores
    float sv[32], tb[32];
    #pragma unroll
    for (int k = 0; k < 32; ++k) {
        float2 v = u.sa[lane + (k << 6)];
        sv[k] = v.x;
        tb[k] = fmaf(sc0, v.x, -v.y);
    }
    __syncthreads();   // sa dead; u.bsum written below

    // prefetch GT windows (latency overlaps pass 1/2)
    int lh[4];
    #pragma unroll
    for (int c = 0; c < 4; ++c) lh[c] = lohi[col * N + row0 + c];

    // pass 1: max of row 0 ONLY (m0 frame)
    float m = -INFINITY;
    #pragma unroll
    for (int k = 0; k < 32; ++k) m = fmaxf(m, tb[k]);
    #pragma unroll
    for (int off = 32; off > 0; off >>= 1)
        m = fmaxf(m, __shfl_xor(m, off, 64));

    // pass 2: se_c = sum_j 2^(t_c - m0); rows 1..3 by incremental multiply
    float se0 = 0.0f, se1 = 0.0f, se2 = 0.0f, se3 = 0.0f;
    #pragma unroll
    for (int k = 0; k < 32; ++k) {
        float g = fexp2(-(sv[k] + sv[k]));
        float E = fexp2(tb[k] - m);
        se0 += E; E *= g;
        se1 += E; E *= g;
        se2 += E; E *= g;
        se3 += E;
    }
    #pragma unroll
    for (int off = 32; off > 0; off >>= 1) {
        se0 += __shfl_xor(se0, off, 64);
        se1 += __shfl_xor(se1, off, 64);
        se2 += __shfl_xor(se2, off, 64);
        se3 += __shfl_xor(se3, off, 64);
    }
    float se[4] = {se0, se1, se2, se3};

    float C2v[4], yv[4];
    unsigned lo[4], wl[4];
    double rbase = 0.0;
    #pragma unroll
    for (int c = 0; c < 4; ++c) {
        float L2 = flog2(se[c]);
        rbase -= 2048.0 * (double)L2;         // -n*L2 term of sum l1
        C2v[c] = CLAMP2 + L2;                 // clamp threshold in (t-m0) units
        lo[c] = (unsigned)(lh[c] & 0xffff);
        wl[c] = (unsigned)((lh[c] >> 16) & 0xffff) - lo[c];
        yv[c] = 1.0f / (float)wl[c];
    }

    // pass 3: a1_c = sum max(log2(se_c - E_c), C2_c); a2_c = windowed (mx1-mx2)
    float a1[4] = {0.0f, 0.0f, 0.0f, 0.0f};
    float a2[4] = {0.0f, 0.0f, 0.0f, 0.0f};
    #pragma unroll
    for (int k = 0; k < 32; ++k) {
        float tsv = sv[k] + sv[k];
        float g = fexp2(-tsv);
        float x = tb[k] - m;
        float E = fexp2(x);
        int j = lane + (k << 6);
        #pragma unroll
        for (int c = 0; c < 4; ++c) {
            float mx2 = fmaxf(flog2(se[c] - E), C2v[c]);
            a1[c] += mx2;
            float mx1 = fmaxf(x, C2v[c]);
            float w = ((unsigned)(j - lo[c]) < wl[c]) ? (mx1 - mx2) : 0.0f;
            a2[c] += w;
            E *= g;     // -> E_{c+1}
            x -= tsv;   // -> x_{c+1}
        }
    }
    #pragma unroll
    for (int off = 32; off > 0; off >>= 1) {
        #pragma unroll
        for (int c = 0; c < 4; ++c) {
            a1[c] += __shfl_xor(a1[c], off, 64);
            a2[c] += __shfl_xor(a2[c], off, 64);
        }
    }
    double rsum = rbase;
    #pragma unroll
    for (int c = 0; c < 4; ++c)
        rsum += (double)a1[c] + (double)yv[c] * (double)a2[c];

    // block combine -> 1 atomic/block -> ticket finalize in last block
    if (lane == 0) u.bsum[wave] = rsum;
    __syncthreads();
    if (tid == 0) {
        double tot = (u.bsum[0] + u.bsum[1]) + (u.bsum[2] + u.bsum[3]);
        atomicAdd(&acc[col], LN2_D * tot);
        __threadfence();
        unsigned old = atomicAdd(counter, 1u);
        if (old == (unsigned)(NC * 128 - 1)) {  // last of 1024 blocks
            __threadfence();
            float ssum = 0.0f;
            int cnt = 0;
            for (int c = 0; c < NC; ++c) {
                double av2 = atomicAdd(&acc[c], 0.0);  // device-scope read
                float lc = (float)(-av2 / ((double)N * (double)N));
                if (lc > 0.0f) { ssum += lc; cnt++; }
            }
            out[0] = ssum / (float)(cnt > 0 ? cnt : 1);
        }
    }
}

extern "C" void kernel_launch(void* const* d_in, const int* in_sizes, int n_in,
                              void* d_out, int out_size, void* d_ws, size_t ws_size,
                              hipStream_t stream) {
    const float* logits    = (const float*)d_in[0];
    const int*   events    = (const int*)d_in[1];
    const float* durations = (const float*)d_in[2];
    float* out = (float*)d_out;

    char* ws = (char*)d_ws;
    double*   acc     = (double*)ws;
    float2*   pack    = (float2*)(ws + 64);
    int*      lohi    = (int*)(ws + 64 + (size_t)NC * N * sizeof(float2));
    unsigned* counter = (unsigned*)(ws + 64 + (size_t)NC * N * (sizeof(float2) + sizeof(int)));

    k_prep<<<dim3(512), 256, 0, stream>>>(logits, durations, events, pack, lohi, acc, counter);
    k_bce<<<dim3(NC * 128), 256, 0, stream>>>(pack, lohi, acc, counter, out);
}